// Round 1
// baseline (644.945 us; speedup 1.0000x reference)
//
#include <hip/hip_runtime.h>
#include <math.h>

#define HWX 16384   // 128*128 pixels per (b, channel) plane

// ---------------------------------------------------------------------------
// 5x5 conv, pad=2, IC=64, over offset_source. Template OC so accumulators
// stay statically indexed (rule: runtime-indexed arrays spill to scratch).
// grid: (64 tiles of 16x16, 2*NCONV);  blockIdx.y: b = y&1, cid = y>>1
// ---------------------------------------------------------------------------
template<int OC, bool SIG>
__global__ __launch_bounds__(256) void conv5x5_kernel(
    const float* __restrict__ src,
    const float* __restrict__ w0c, const float* __restrict__ b0c,
    const float* __restrict__ w1c, const float* __restrict__ b1c,
    const float* __restrict__ w2c, const float* __restrict__ b2c,
    const float* __restrict__ w3c, const float* __restrict__ b3c,
    float* __restrict__ outbase)
{
    const int by  = blockIdx.y;
    const int b   = by & 1;
    const int cid = by >> 1;
    const int tile = blockIdx.x;
    const int y0 = (tile >> 3) << 4;
    const int x0 = (tile & 7) << 4;

    const float* w; const float* bias;
    switch (cid) {
        case 0:  w = w0c; bias = b0c; break;
        case 1:  w = w1c; bias = b1c; break;
        case 2:  w = w2c; bias = b2c; break;
        default: w = w3c; bias = b3c; break;
    }
    float* outp = outbase + cid * (2 * OC * HWX) + ((b * OC) << 14);

    const int t = threadIdx.x;
    const int ty = t >> 4, tx = t & 15;
    const int y = y0 + ty, x = x0 + tx;

    float acc[OC];
    #pragma unroll
    for (int j = 0; j < OC; ++j) acc[j] = bias[j];

    __shared__ float tile_s[400];   // 20x20 halo tile, one input channel

    for (int ic = 0; ic < 64; ++ic) {
        for (int idx = t; idx < 400; idx += 256) {
            const int yy = y0 - 2 + idx / 20;
            const int xx = x0 - 2 + idx % 20;
            float v = 0.f;
            if (yy >= 0 && yy < 128 && xx >= 0 && xx < 128)
                v = src[(((b << 6) + ic) << 14) + (yy << 7) + xx];
            tile_s[idx] = v;
        }
        __syncthreads();
        float r[25];
        #pragma unroll
        for (int ky = 0; ky < 5; ++ky)
            #pragma unroll
            for (int kx = 0; kx < 5; ++kx)
                r[ky * 5 + kx] = tile_s[(ty + ky) * 20 + tx + kx];
        const float* wr = w + ic * 25;
        #pragma unroll
        for (int j = 0; j < OC; ++j) {
            const float* wj = wr + j * 1600;   // w[(j*64+ic)*25]
            #pragma unroll
            for (int k = 0; k < 25; ++k)
                acc[j] = fmaf(wj[k], r[k], acc[j]);
        }
        __syncthreads();
    }
    const int p = (y << 7) + x;
    #pragma unroll
    for (int j = 0; j < OC; ++j) {
        float v = acc[j];
        if (SIG) {
            v = 1.f / (1.f + expf(-v));
            if (cid == 0) v *= 3.f;   // z = 3*sigmoid(.)
        }
        outp[(j << 14) + p] = v;
    }
}

// ---------------------------------------------------------------------------
// Transpose img[b,c,y,x] -> imgT[img][b][p][c]  (channel-last for coalesced
// gathers in the fused kernel). grid (256 p-tiles, B=2, 4 images), block 256.
// ---------------------------------------------------------------------------
__global__ __launch_bounds__(256) void transpose_kernel(
    const float* __restrict__ i0, const float* __restrict__ i1,
    const float* __restrict__ i2, const float* __restrict__ i3,
    float* __restrict__ imgT)
{
    const int img = blockIdx.z;
    const int b   = blockIdx.y;
    const int p0  = blockIdx.x << 6;
    const float* src = (img == 0) ? i0 : (img == 1) ? i1 : (img == 2) ? i2 : i3;

    __shared__ float tile[64][65];
    const int t = threadIdx.x;
    const int pp = t & 63, c0 = t >> 6;
    #pragma unroll
    for (int k = 0; k < 16; ++k) {
        const int c = (k << 2) + c0;
        tile[c][pp] = src[(((b << 6) + c) << 14) + p0 + pp];
    }
    __syncthreads();
    const int c = t & 63, pl = t >> 6;
    #pragma unroll
    for (int k = 0; k < 16; ++k) {
        const int pi = (k << 2) + pl;
        imgT[((((img << 1) + b) << 14) + p0 + pi) * 64 + c] = tile[c][pi];
    }
}

// ---------------------------------------------------------------------------
// WcT[(c*9+n)*64 + o] = w_conv[o,c,n]  (coalesced-over-o layout for phase C)
// ---------------------------------------------------------------------------
__global__ __launch_bounds__(256) void wct_kernel(
    const float* __restrict__ wc, float* __restrict__ WcT)
{
    const int idx = blockIdx.x * 256 + threadIdx.x;   // 36864 total
    if (idx < 36864) {
        const int cn = idx >> 6;
        const int o  = idx & 63;
        WcT[idx] = wc[o * 576 + cn];
    }
}

// ---------------------------------------------------------------------------
// Fused deform-sample + weighted-sum + final contraction.
// One block = 16 consecutive pixels of one row of one batch.
//   A: 576 units (16px x 4img x 9n) -> tap indices + combined weights (LDS)
//   B: s[c][n] per pixel via coalesced channel-last gathers -> LDS
//   C: out[o,px] = sum_cn WcT[cn,o] * s[px,cn]
//   D: LDS-staged coalesced store
// ---------------------------------------------------------------------------
__global__ __launch_bounds__(256) void fused_kernel(
    const float* __restrict__ offs,   // [4][2][18][HWX]
    const float* __restrict__ zbuf,   // [2][9][HWX]
    const float* __restrict__ mbuf,   // [2][9][HWX]
    const float* __restrict__ imgT,   // [4][2][HWX][64]
    const float* __restrict__ WcT,    // [576][64]
    float* __restrict__ out)          // [2][64][HWX]
{
    __shared__ __align__(16) float s_s[16 * 576];    // 36864 B
    __shared__ int4   s_ti4[16 * 36];                // 9216 B
    __shared__ float4 s_tw4[16 * 36];                // 9216 B

    const int t   = threadIdx.x;
    const int pid = blockIdx.x;          // 2048 blocks
    const int b   = pid >> 10;
    const int rem = pid & 1023;
    const int h   = rem >> 3;
    const int w0p = (rem & 7) << 4;

    // ---- phase A: taps ----
    for (int u = t; u < 576; u += 256) {
        const int px   = u / 36;
        const int unit = u - px * 36;
        const int i    = unit / 9;
        const int n    = unit - i * 9;
        const int wcol = w0p + px;
        const int p    = (h << 7) + wcol;

        const float* ob = offs + i * (2 * 18 * HWX) + ((b * 18) << 14);
        const float ox = ob[(n << 14) + p];
        const float oy = ob[((n + 9) << 14) + p];
        const float z  = zbuf[((b * 9 + n) << 14) + p];
        const float mm = mbuf[((b * 9 + n) << 14) + p];

        // cubic basis coefficients per image (modes '1','2','4',else)
        const float zc0 = (i == 0) ? 1.f : 0.f;
        const float zc1 = (i == 0) ? (-11.f / 6.f) : (i == 1) ? 3.f
                         : (i == 2) ? -1.5f : (1.f / 3.f);
        const float zc2 = (i == 0) ? 1.f : (i == 1) ? -2.5f
                         : (i == 2) ? 2.f : -0.5f;
        const float zc3 = (i == 0) ? (-1.f / 6.f) : (i == 1) ? 0.5f
                         : (i == 2) ? -0.5f : (1.f / 6.f);
        const float zw   = zc0 + z * (zc1 + z * (zc2 + z * zc3));
        const float coef = zw * mm;

        const float pxf = (float)(h + n / 3) + ox;       // (h+PAD)+(n/3-1)
        const float pyf = (float)(wcol + n % 3) + oy;
        const float flx = floorf(pxf), fly = floorf(pyf);
        const float qltx = fminf(fmaxf(flx, 0.f), 129.f);
        const float qrbx = fminf(fmaxf(flx + 1.f, 0.f), 129.f);
        const float qlty = fminf(fmaxf(fly, 0.f), 129.f);
        const float qrby = fminf(fmaxf(fly + 1.f, 0.f), 129.f);
        const float pxc = fminf(fmaxf(pxf, 0.f), 129.f);
        const float pyc = fminf(fmaxf(pyf, 0.f), 129.f);
        const float gxl = 1.f + (qltx - pxc);
        const float gxr = 1.f - (qrbx - pxc);
        const float gyl = 1.f + (qlty - pyc);
        const float gyr = 1.f - (qrby - pyc);
        const int ixl = (int)qltx, ixr = (int)qrbx;
        const int iyl = (int)qlty, iyr = (int)qrby;

        int4 ti; float4 tw;
        auto mk = [&](int qx, int qy, float g, int& ii, float& ww) {
            const bool valid = (qx >= 1) && (qx <= 128) && (qy >= 1) && (qy <= 128);
            ii = valid ? (((qx - 1) << 7) + (qy - 1)) : 0;   // unpadded pixel idx
            ww = valid ? g * coef : 0.f;                     // pad ring = zeros
        };
        mk(ixl, iyl, gxl * gyl, ti.x, tw.x);   // lt
        mk(ixr, iyr, gxr * gyr, ti.y, tw.y);   // rb
        mk(ixr, iyl, gxr * gyl, ti.z, tw.z);   // lb
        mk(ixl, iyr, gxl * gyr, ti.w, tw.w);   // rt
        s_ti4[u] = ti;
        s_tw4[u] = tw;
    }
    __syncthreads();

    // ---- phase B: sample s[px][c][n] ----
    const int c  = t & 63;
    const int wv = t >> 6;
    #pragma unroll 1
    for (int q = 0; q < 4; ++q) {
        const int px = (wv << 2) + q;
        float s[9];
        #pragma unroll
        for (int n = 0; n < 9; ++n) s[n] = 0.f;
        const int tb = px * 36;
        #pragma unroll
        for (int i = 0; i < 4; ++i) {
            const float* ib = imgT + ((((i << 1) + b) << 14) << 6) + c;
            #pragma unroll
            for (int n = 0; n < 9; ++n) {
                const int4   ti = s_ti4[tb + i * 9 + n];
                const float4 tw = s_tw4[tb + i * 9 + n];
                s[n] = fmaf(tw.x, ib[ti.x << 6], s[n]);
                s[n] = fmaf(tw.y, ib[ti.y << 6], s[n]);
                s[n] = fmaf(tw.z, ib[ti.z << 6], s[n]);
                s[n] = fmaf(tw.w, ib[ti.w << 6], s[n]);
            }
        }
        float* sp = s_s + px * 576 + c * 9;
        #pragma unroll
        for (int n = 0; n < 9; ++n) sp[n] = s[n];
    }
    __syncthreads();

    // ---- phase C: contraction out[o, px] ----
    const int o = t & 63;
    float acc0 = 0.f, acc1 = 0.f, acc2 = 0.f, acc3 = 0.f;
    const float* s0 = s_s + ((wv << 2) + 0) * 576;
    const float* s1 = s_s + ((wv << 2) + 1) * 576;
    const float* s2 = s_s + ((wv << 2) + 2) * 576;
    const float* s3 = s_s + ((wv << 2) + 3) * 576;
    #pragma unroll 2
    for (int cn = 0; cn < 576; cn += 4) {
        const float wv0 = WcT[(cn + 0) * 64 + o];
        const float wv1 = WcT[(cn + 1) * 64 + o];
        const float wv2 = WcT[(cn + 2) * 64 + o];
        const float wv3 = WcT[(cn + 3) * 64 + o];
        const float4 a = *(const float4*)(s0 + cn);
        const float4 e = *(const float4*)(s1 + cn);
        const float4 f = *(const float4*)(s2 + cn);
        const float4 g = *(const float4*)(s3 + cn);
        acc0 = fmaf(wv0, a.x, acc0); acc0 = fmaf(wv1, a.y, acc0);
        acc0 = fmaf(wv2, a.z, acc0); acc0 = fmaf(wv3, a.w, acc0);
        acc1 = fmaf(wv0, e.x, acc1); acc1 = fmaf(wv1, e.y, acc1);
        acc1 = fmaf(wv2, e.z, acc1); acc1 = fmaf(wv3, e.w, acc1);
        acc2 = fmaf(wv0, f.x, acc2); acc2 = fmaf(wv1, f.y, acc2);
        acc2 = fmaf(wv2, f.z, acc2); acc2 = fmaf(wv3, f.w, acc2);
        acc3 = fmaf(wv0, g.x, acc3); acc3 = fmaf(wv1, g.y, acc3);
        acc3 = fmaf(wv2, g.z, acc3); acc3 = fmaf(wv3, g.w, acc3);
    }

    // ---- phase D: staged coalesced store ----
    float* s_out = (float*)s_tw4;     // reuse, stride 17 to dodge bank conflicts
    s_out[o * 17 + (wv << 2) + 0] = acc0;
    s_out[o * 17 + (wv << 2) + 1] = acc1;
    s_out[o * 17 + (wv << 2) + 2] = acc2;
    s_out[o * 17 + (wv << 2) + 3] = acc3;
    __syncthreads();
    #pragma unroll
    for (int k = 0; k < 4; ++k) {
        const int idx = t + (k << 8);
        const int oo  = idx >> 4;
        const int pxl = idx & 15;
        out[(((b << 6) + oo) << 14) + (h << 7) + w0p + pxl] = s_out[oo * 17 + pxl];
    }
}

// ---------------------------------------------------------------------------
extern "C" void kernel_launch(void* const* d_in, const int* in_sizes, int n_in,
                              void* d_out, int out_size, void* d_ws, size_t ws_size,
                              hipStream_t stream) {
    (void)in_sizes; (void)n_in; (void)out_size; (void)ws_size;
    const float* img1  = (const float*)d_in[0];
    const float* img2  = (const float*)d_in[1];
    const float* img4  = (const float*)d_in[2];
    const float* img5  = (const float*)d_in[3];
    const float* osrc  = (const float*)d_in[4];
    const float* w_pc1 = (const float*)d_in[5];
    const float* b_pc1 = (const float*)d_in[6];
    const float* w_pc2 = (const float*)d_in[7];
    const float* b_pc2 = (const float*)d_in[8];
    const float* w_pc4 = (const float*)d_in[9];
    const float* b_pc4 = (const float*)d_in[10];
    const float* w_pc5 = (const float*)d_in[11];
    const float* b_pc5 = (const float*)d_in[12];
    const float* w_z   = (const float*)d_in[13];
    const float* b_z   = (const float*)d_in[14];
    const float* w_m   = (const float*)d_in[15];
    const float* b_m   = (const float*)d_in[16];
    const float* w_cv  = (const float*)d_in[17];
    float* out = (float*)d_out;

    float* wsf  = (float*)d_ws;
    float* offs = wsf;                    // 4 * 589824 = 2359296 floats
    float* zbuf = wsf + 4 * 589824;       // 294912
    float* mbuf = zbuf + 294912;          // 294912
    float* WcT  = mbuf + 294912;          // 36864
    float* imgT = WcT + 36864;            // 8388608   (total ~45.5 MB)

    conv5x5_kernel<18, false><<<dim3(64, 8), 256, 0, stream>>>(
        osrc, w_pc1, b_pc1, w_pc2, b_pc2, w_pc4, b_pc4, w_pc5, b_pc5, offs);
    conv5x5_kernel<9, true><<<dim3(64, 4), 256, 0, stream>>>(
        osrc, w_z, b_z, w_m, b_m, w_m, b_m, w_m, b_m, zbuf);
    transpose_kernel<<<dim3(256, 2, 4), 256, 0, stream>>>(img1, img2, img4, img5, imgT);
    wct_kernel<<<dim3(144), 256, 0, stream>>>(w_cv, WcT);
    fused_kernel<<<dim3(2048), 256, 0, stream>>>(offs, zbuf, mbuf, imgT, WcT, out);
}